// Round 1
// baseline (922.729 us; speedup 1.0000x reference)
//
#include <hip/hip_runtime.h>

typedef __attribute__((ext_vector_type(8))) short short8;
typedef __attribute__((ext_vector_type(4))) float f32x4;

__device__ __forceinline__ unsigned short f2bf(float f) {
  union { float f; unsigned u; } v; v.f = f;
  unsigned r = v.u + 0x7fffu + ((v.u >> 16) & 1u);
  return (unsigned short)(r >> 16);
}

__device__ __forceinline__ void async16(const void* g, void* l) {
  __builtin_amdgcn_global_load_lds(
      (const __attribute__((address_space(1))) unsigned*)g,
      (__attribute__((address_space(3))) unsigned*)l, 16, 0, 0);
}

// ---------------- fp32 -> bf16 bulk convert ----------------
__global__ void cvt_bf16_kernel(const float4* __restrict__ in,
                                ushort4* __restrict__ out, int n4) {
  int i = blockIdx.x * blockDim.x + threadIdx.x;
  int stride = gridDim.x * blockDim.x;
  for (; i < n4; i += stride) {
    float4 v = in[i];
    ushort4 o;
    o.x = f2bf(v.x); o.y = f2bf(v.y); o.z = f2bf(v.z); o.w = f2bf(v.w);
    out[i] = o;
  }
}

// ---------------- W_eff[e] = W + 2.0 * b[e] @ a[e], output bf16 ----------------
// w: [J][K] f32, b: [E][J][64] f32, a: [E][64][K] f32, out: [E][J][K] bf16
__global__ void make_weff(const float* __restrict__ w,
                          const float* __restrict__ bmat,
                          const float* __restrict__ amat,
                          unsigned short* __restrict__ out,
                          int J, int K) {
  const int e = blockIdx.y;
  const float* a = amat + (size_t)e * 64 * K;
  const float* b = bmat + (size_t)e * J * 64;
  const int j0 = blockIdx.x * 16;
  __shared__ float bs[16][64];
  const int tid = threadIdx.x;
  for (int i = tid; i < 16 * 64; i += 256)
    bs[i >> 6][i & 63] = b[(size_t)(j0 + (i >> 6)) * 64 + (i & 63)];
  __syncthreads();
  for (int k = tid; k < K; k += 256) {
    float acc[16];
#pragma unroll
    for (int jj = 0; jj < 16; ++jj) acc[jj] = 0.f;
    for (int r = 0; r < 64; ++r) {
      float av = a[(size_t)r * K + k];
#pragma unroll
      for (int jj = 0; jj < 16; ++jj) acc[jj] += bs[jj][r] * av;
    }
#pragma unroll
    for (int jj = 0; jj < 16; ++jj) {
      float v = w[(size_t)(j0 + jj) * K + k] + 2.0f * acc[jj];
      out[((size_t)e * J + j0 + jj) * K + k] = f2bf(v);
    }
  }
}

// ---------------- grouped GEMM: C[m][n] = A[m][:] . Bw[e][n][:] + bias[n] ----------------
// A: [40960][K] bf16 (tokens), Bw: [2][N][K] bf16, expert by token tile.
// 128x128 tile, BK=32, 4 waves, 16x16x32 bf16 MFMA (m97 structure).
template <bool FUSE_GELU, bool OUT_BF16>
__global__ __launch_bounds__(256) void gemm_bt(
    const unsigned short* __restrict__ A,
    const unsigned short* __restrict__ Bw,
    const float* __restrict__ bias,
    void* __restrict__ Cout,
    int N, int K) {
  __shared__ unsigned short As[128][32];
  __shared__ unsigned short Bs[128][32];

  const int tid = threadIdx.x;
  const int wid = tid >> 6, lane = tid & 63;
  const int m0 = blockIdx.y * 128, n0 = blockIdx.x * 128;
  // expert from seq position: s%1280 < 256 -> expert 0 else 1 (tiles are aligned)
  const int e = ((blockIdx.y * 128) % 1280) < 256 ? 0 : 1;
  const unsigned short* Bp = Bw + (size_t)e * N * K;

  const int srow = lane >> 2;       // 0..15 row within 16-row chunk
  const int skk = (lane & 3) * 8;   // bf16 element offset within 32-wide row

  const int fr = lane & 15;
  const int fk = (lane >> 4) * 8;
  const int wr = wid >> 1, wc = wid & 1;

  f32x4 acc[4][4] = {};

  for (int k0 = 0; k0 < K; k0 += 32) {
#pragma unroll
    for (int i = 0; i < 2; ++i) {
      const int r = wid * 32 + i * 16;  // wave-uniform chunk base row
      async16(A + (size_t)(m0 + r + srow) * K + k0 + skk, &As[r][0]);
      async16(Bp + (size_t)(n0 + r + srow) * K + k0 + skk, &Bs[r][0]);
    }
    __syncthreads();

    short8 af[4], bfr[4];
#pragma unroll
    for (int m = 0; m < 4; ++m)
      af[m] = *(const short8*)&As[wr * 64 + m * 16 + fr][fk];
#pragma unroll
    for (int n = 0; n < 4; ++n)
      bfr[n] = *(const short8*)&Bs[wc * 64 + n * 16 + fr][fk];
#pragma unroll
    for (int m = 0; m < 4; ++m)
#pragma unroll
      for (int n = 0; n < 4; ++n)
        acc[m][n] = __builtin_amdgcn_mfma_f32_16x16x32_bf16(af[m], bfr[n],
                                                            acc[m][n], 0, 0, 0);
    __syncthreads();
  }

  // Epilogue: C/D layout col=lane&15, row=(lane>>4)*4+j (m89/m91-verified)
  const int crow0 = m0 + wr * 64 + (lane >> 4) * 4;
  const int ccol0 = n0 + wc * 64 + (lane & 15);
#pragma unroll
  for (int m = 0; m < 4; ++m) {
#pragma unroll
    for (int n = 0; n < 4; ++n) {
      const int col = ccol0 + n * 16;
      const float bv = bias[col];
#pragma unroll
      for (int j = 0; j < 4; ++j) {
        const int row = crow0 + m * 16 + j;
        float v = acc[m][n][j] + bv;
        if (FUSE_GELU) v = 0.5f * v * (1.0f + erff(v * 0.70710678118f));
        if (OUT_BF16)
          ((unsigned short*)Cout)[(size_t)row * N + col] = f2bf(v);
        else
          ((float*)Cout)[(size_t)row * N + col] = v;
      }
    }
  }
}

extern "C" void kernel_launch(void* const* d_in, const int* in_sizes, int n_in,
                              void* d_out, int out_size, void* d_ws,
                              size_t ws_size, hipStream_t stream) {
  const float* x = (const float*)d_in[0];
  const float* w1 = (const float*)d_in[1];
  const float* bias1 = (const float*)d_in[2];
  const float* a1 = (const float*)d_in[3];
  const float* b1 = (const float*)d_in[4];
  const float* w2 = (const float*)d_in[5];
  const float* bias2 = (const float*)d_in[6];
  const float* a2 = (const float*)d_in[7];
  const float* b2 = (const float*)d_in[8];
  float* out = (float*)d_out;

  // B=32, S=1280 (chunks 256/1024 -> experts 0/1), IN=768, HID=3072, OUT=768
  // M = 40960 tokens
  char* ws = (char*)d_ws;
  unsigned short* x_bf = (unsigned short*)(ws + 0);          // 40960*768  bf16
  unsigned short* w1e = (unsigned short*)(ws + 62914560);    // 2*3072*768 bf16
  unsigned short* w2e = (unsigned short*)(ws + 72351744);    // 2*768*3072 bf16
  unsigned short* h = (unsigned short*)(ws + 81788928);      // 40960*3072 bf16

  cvt_bf16_kernel<<<2048, 256, 0, stream>>>((const float4*)x, (ushort4*)x_bf,
                                            40960 * 768 / 4);
  make_weff<<<dim3(3072 / 16, 2), 256, 0, stream>>>(w1, b1, a1, w1e, 3072, 768);
  make_weff<<<dim3(768 / 16, 2), 256, 0, stream>>>(w2, b2, a2, w2e, 768, 3072);

  gemm_bt<true, true><<<dim3(3072 / 128, 40960 / 128), 256, 0, stream>>>(
      x_bf, w1e, bias1, h, 3072, 768);
  gemm_bt<false, false><<<dim3(768 / 128, 40960 / 128), 256, 0, stream>>>(
      h, w2e, bias2, out, 768, 3072);
}

// Round 3
// 742.333 us; speedup vs baseline: 1.2430x; 1.2430x over previous
//
#include <hip/hip_runtime.h>

typedef __attribute__((ext_vector_type(8))) short short8;
typedef __attribute__((ext_vector_type(4))) float f32x4;

__device__ __forceinline__ unsigned short f2bf(float f) {
  union { float f; unsigned u; } v; v.f = f;
  unsigned r = v.u + 0x7fffu + ((v.u >> 16) & 1u);
  return (unsigned short)(r >> 16);
}

__device__ __forceinline__ void async16(const void* g, void* l) {
  __builtin_amdgcn_global_load_lds(
      (const __attribute__((address_space(1))) unsigned*)g,
      (__attribute__((address_space(3))) unsigned*)l, 16, 0, 0);
}

#define BARRIER() __builtin_amdgcn_s_barrier()
#define LGKM0()                                                     \
  do {                                                              \
    asm volatile("s_waitcnt lgkmcnt(0)" ::: "memory");              \
    __builtin_amdgcn_sched_barrier(0);                              \
  } while (0)
#define WAIT_VM(N) asm volatile("s_waitcnt vmcnt(" #N ")" ::: "memory")

// ---------------- fp32 -> bf16 bulk convert ----------------
__global__ void cvt_bf16_kernel(const float4* __restrict__ in,
                                ushort4* __restrict__ out, int n4) {
  int i = blockIdx.x * blockDim.x + threadIdx.x;
  int stride = gridDim.x * blockDim.x;
  for (; i < n4; i += stride) {
    float4 v = in[i];
    ushort4 o;
    o.x = f2bf(v.x); o.y = f2bf(v.y); o.z = f2bf(v.z); o.w = f2bf(v.w);
    out[i] = o;
  }
}

// ---------------- W_eff[e] = W + 2.0 * b[e] @ a[e], output bf16 ----------------
__global__ void make_weff(const float* __restrict__ w,
                          const float* __restrict__ bmat,
                          const float* __restrict__ amat,
                          unsigned short* __restrict__ out,
                          int J, int K) {
  const int e = blockIdx.y;
  const float* a = amat + (size_t)e * 64 * K;
  const float* b = bmat + (size_t)e * J * 64;
  const int j0 = blockIdx.x * 16;
  __shared__ float bs[16][64];
  const int tid = threadIdx.x;
  for (int i = tid; i < 16 * 64; i += 256)
    bs[i >> 6][i & 63] = b[(size_t)(j0 + (i >> 6)) * 64 + (i & 63)];
  __syncthreads();
  for (int k = tid; k < K; k += 256) {
    float acc[16];
#pragma unroll
    for (int jj = 0; jj < 16; ++jj) acc[jj] = 0.f;
    for (int r = 0; r < 64; ++r) {
      float av = a[(size_t)r * K + k];
#pragma unroll
      for (int jj = 0; jj < 16; ++jj) acc[jj] += bs[jj][r] * av;
    }
#pragma unroll
    for (int jj = 0; jj < 16; ++jj) {
      float v = w[(size_t)(j0 + jj) * K + k] + 2.0f * acc[jj];
      out[((size_t)e * J + j0 + jj) * K + k] = f2bf(v);
    }
  }
}

// ---------------- 256x256 8-phase grouped GEMM (HK schedule, plain HIP) -------
// A: [M][K] bf16, Bw: [2][N][K] bf16 (expert per 256-row M tile), bias f32.
// 8 waves (2M x 4N), BK=64, double-buffered 128 KiB LDS.
// LDS image per matrix/buf: [256][64] bf16 (row stride 128 B), swizzle:
// LDS[row][16B-slot j] holds global 16B-chunk j ^ (row&7)  (both-sides XOR).
// Quadrants align with 128-row halves:
//   A rows: (mbase>>2)*128 + wr*64 + m_*16 + fr   (mbase=0 -> half0 exactly)
//   B rows: (nbase>>1)*128 + wc*32 + n_*16 + fr   (nbase=0 -> half0 exactly)
// Read phases per tile: P1 {A h0, B h0}, P2 {B h1}, P3 {A h1}, P4 none.
// Stage schedule (region's last read strictly earlier):
//   P1: A1h1(t+1)  P2: A0h0(t+2)  P3: B0h0(t+2)  P4: B0h1(t+2) +vmcnt(6)
//   P5: A0h1(t+2)  P6: A1h0(t+3)  P7: B1h0(t+3)  P8: B1h1(t+3) +vmcnt(6)

#define STAGE(Xp, Xs, half, t)                                                 \
  do {                                                                         \
    const unsigned short* _g =                                                 \
        (Xp) + (size_t)((half) * 128) * K + (size_t)(t) * 64 + gstep;          \
    unsigned short* _l = (Xs) + (half) * 8192 + loff;                          \
    async16(_g, _l);                                                           \
    async16(_g + (size_t)64 * K, _l + 4096);                                   \
  } while (0)

#define RDA(Xs, mbase)                                                         \
  _Pragma("unroll") for (int m_ = 0; m_ < 4; ++m_)                             \
  _Pragma("unroll") for (int kk_ = 0; kk_ < 2; ++kk_)                          \
      afm[m_][kk_] = *(const short8*)((const char*)(Xs) +                      \
                                      ((mbase) >> 2) * 16384 + arowB +         \
                                      m_ * 2048 + cb[kk_]);

#define RDB(Xs, nbase)                                                         \
  _Pragma("unroll") for (int n_ = 0; n_ < 2; ++n_)                             \
  _Pragma("unroll") for (int kk_ = 0; kk_ < 2; ++kk_)                          \
      bfv[(nbase) + n_][kk_] = *(const short8*)((const char*)(Xs) +            \
                                                ((nbase) >> 1) * 16384 +       \
                                                browB + n_ * 2048 + cb[kk_]);

#define MFMAQ(mbase, nbase)                                                    \
  __builtin_amdgcn_s_setprio(1);                                               \
  _Pragma("unroll") for (int m_ = 0; m_ < 4; ++m_)                             \
  _Pragma("unroll") for (int n_ = 0; n_ < 2; ++n_)                             \
  _Pragma("unroll") for (int kk_ = 0; kk_ < 2; ++kk_)                          \
      acc[(mbase) + m_][(nbase) + n_] =                                        \
          __builtin_amdgcn_mfma_f32_16x16x32_bf16(                             \
              afm[m_][kk_], bfv[(nbase) + n_][kk_],                            \
              acc[(mbase) + m_][(nbase) + n_], 0, 0, 0);                       \
  __builtin_amdgcn_s_setprio(0);

template <bool FUSE_GELU, bool OUT_BF16>
__global__ __launch_bounds__(512, 2) void gemm256(
    const unsigned short* __restrict__ A, const unsigned short* __restrict__ Bw,
    const float* __restrict__ bias, void* __restrict__ Cout, int N, int K,
    int NXT) {
  extern __shared__ unsigned short lds[];
  unsigned short* As0 = lds;
  unsigned short* As1 = lds + 16384;
  unsigned short* Bs0 = lds + 32768;
  unsigned short* Bs1 = lds + 49152;

  const int tid = threadIdx.x;
  const int w = tid >> 6, lane = tid & 63;

  // XCD-aware bijective swizzle (gridDim.x % 8 == 0 by construction)
  const int nwg = gridDim.x, bid = blockIdx.x;
  const int qchunk = nwg >> 3;
  const int wg = (bid & 7) * qchunk + (bid >> 3);
  const int by = wg / NXT, bx = wg - by * NXT;
  const int m0 = by << 8, n0 = bx << 8;
  const int e = (m0 % 1280) ? 1 : 0;  // 256-aligned tiles never span experts
  const unsigned short* Ap = A + (size_t)m0 * K;
  const unsigned short* Bp = Bw + ((size_t)e * N + n0) * K;

  const int wr = w >> 2, wc = w & 3;
  const int fr = lane & 15;
  const int swz = (fr & 7) << 4;
  const int cb[2] = {(((lane >> 4) << 4) + 0) ^ swz,
                     (((lane >> 4) << 4) + 64) ^ swz};
  const int arowB = (wr * 64 + fr) * 128;  // byte base of A frag rows (in half)
  const int browB = (wc * 32 + fr) * 128;  // byte base of B frag rows (in half)

  // staging: thread covers row (w*8 + (lane>>3)) + {0,64}, 16B chunk c16
  const int rql = lane >> 3;
  const int c16 = (lane & 7) ^ rql;  // inverse-swizzled source chunk
  const size_t gstep = (size_t)(w * 8 + rql) * K + c16 * 8;
  const int loff = w * 512;  // wave-uniform LDS base (HW adds lane*16B)

  f32x4 acc[8][4] = {};
  short8 afm[4][2];
  short8 bfv[4][2];

  const int T = K >> 6;  // # of 64-wide K tiles (12 or 48, even)
  const int niter = T >> 1;

  // ---- prologue: tile0 (buf0) fully staged; tile1 {A1h0,B1h0,B1h1} in flight
  STAGE(Ap, As0, 0, 0); STAGE(Ap, As0, 1, 0);
  STAGE(Bp, Bs0, 0, 0); STAGE(Bp, Bs0, 1, 0);
  STAGE(Ap, As1, 0, 1);
  STAGE(Bp, Bs1, 0, 1); STAGE(Bp, Bs1, 1, 1);
  WAIT_VM(6);  // tile0's 8 loads landed; 6 in flight
  BARRIER();

  for (int i = 0; i < niter; ++i) {
    const int t1 = 2 * i + 1;
    int u2 = 2 * i + 2; if (u2 >= T) u2 -= T;  // wrap: never-read garbage,
    int u3 = 2 * i + 3; if (u3 >= T) u3 -= T;  // keeps vmcnt counts exact

    // P1: tile 2i (A h0 x B h0); stage A1h1(2i+1) [A1h1 last read prev P7]
    RDA(As0, 0); RDB(Bs0, 0);
    STAGE(Ap, As1, 1, t1);
    BARRIER(); LGKM0();
    MFMAQ(0, 0);
    BARRIER();
    // P2: (A h0 x B h1); stage A0h0(2i+2) [A h0 last read P1]
    RDB(Bs0, 2);
    STAGE(Ap, As0, 0, u2);
    BARRIER(); LGKM0();
    MFMAQ(0, 2);
    BARRIER();
    // P3: (A h1 x B h0); stage B0h0(2i+2) [B h0 last read P1]
    RDA(As0, 4);
    STAGE(Bp, Bs0, 0, u2);
    BARRIER(); LGKM0();
    MFMAQ(4, 0);
    BARRIER();
    // P4: (A h1 x B h1); stage B0h1(2i+2) [B h1 last read P2]; drain -> tile 2i+1
    STAGE(Bp, Bs0, 1, u2);
    BARRIER();
    MFMAQ(4, 2);
    WAIT_VM(6);
    BARRIER();
    // P5: tile 2i+1 (A h0 x B h0); stage A0h1(2i+2) [A h1 last read P3]
    RDA(As1, 0); RDB(Bs1, 0);
    STAGE(Ap, As0, 1, u2);
    BARRIER(); LGKM0();
    MFMAQ(0, 0);
    BARRIER();
    // P6: (A h0 x B h1); stage A1h0(2i+3) [As1 h0 last read P5]
    RDB(Bs1, 2);
    STAGE(Ap, As1, 0, u3);
    BARRIER(); LGKM0();
    MFMAQ(0, 2);
    BARRIER();
    // P7: (A h1 x B h0); stage B1h0(2i+3) [Bs1 h0 last read P5]
    RDA(As1, 4);
    STAGE(Bp, Bs1, 0, u3);
    BARRIER(); LGKM0();
    MFMAQ(4, 0);
    BARRIER();
    // P8: (A h1 x B h1); stage B1h1(2i+3) [Bs1 h1 last read P6]; drain
    STAGE(Bp, Bs1, 1, u3);
    BARRIER();
    MFMAQ(4, 2);
    WAIT_VM(6);
    BARRIER();
  }

  // ---- epilogue: C/D layout col=lane&15, row=(lane>>4)*4+j ----
  const int lrow = (lane >> 4) << 2;
#pragma unroll
  for (int mi = 0; mi < 8; ++mi) {
    const int rbase = m0 + ((mi >> 2) << 7) + wr * 64 + ((mi & 3) << 4) + lrow;
#pragma unroll
    for (int n = 0; n < 4; ++n) {
      const int col = n0 + ((n >> 1) << 7) + wc * 32 + ((n & 1) << 4) + fr;
      const float bv = bias[col];
#pragma unroll
      for (int j = 0; j < 4; ++j) {
        const int row = rbase + j;
        float v = acc[mi][n][j] + bv;
        if (FUSE_GELU) v = 0.5f * v * (1.0f + erff(v * 0.70710678118f));
        if (OUT_BF16)
          ((unsigned short*)Cout)[(size_t)row * N + col] = f2bf(v);
        else
          ((float*)Cout)[(size_t)row * N + col] = v;
      }
    }
  }
}

extern "C" void kernel_launch(void* const* d_in, const int* in_sizes, int n_in,
                              void* d_out, int out_size, void* d_ws,
                              size_t ws_size, hipStream_t stream) {
  const float* x = (const float*)d_in[0];
  const float* w1 = (const float*)d_in[1];
  const float* bias1 = (const float*)d_in[2];
  const float* a1 = (const float*)d_in[3];
  const float* b1 = (const float*)d_in[4];
  const float* w2 = (const float*)d_in[5];
  const float* bias2 = (const float*)d_in[6];
  const float* a2 = (const float*)d_in[7];
  const float* b2 = (const float*)d_in[8];
  float* out = (float*)d_out;

  char* ws = (char*)d_ws;
  unsigned short* x_bf = (unsigned short*)(ws + 0);        // 40960*768 bf16
  unsigned short* w1e = (unsigned short*)(ws + 62914560);  // 2*3072*768 bf16
  unsigned short* w2e = (unsigned short*)(ws + 72351744);  // 2*768*3072 bf16
  unsigned short* h = (unsigned short*)(ws + 81788928);    // 40960*3072 bf16

  hipFuncSetAttribute(reinterpret_cast<const void*>(&gemm256<true, true>),
                      hipFuncAttributeMaxDynamicSharedMemorySize, 131072);
  hipFuncSetAttribute(reinterpret_cast<const void*>(&gemm256<false, false>),
                      hipFuncAttributeMaxDynamicSharedMemorySize, 131072);

  cvt_bf16_kernel<<<4096, 256, 0, stream>>>((const float4*)x, (ushort4*)x_bf,
                                            40960 * 768 / 4);
  make_weff<<<dim3(3072 / 16, 2), 256, 0, stream>>>(w1, b1, a1, w1e, 3072, 768);
  make_weff<<<dim3(768 / 16, 2), 256, 0, stream>>>(w2, b2, a2, w2e, 768, 3072);

  // M=40960 -> 160 M-tiles; GEMM1: 160x12=1920 wgs; GEMM2: 160x3=480 wgs
  gemm256<true, true><<<1920, 512, 131072, stream>>>(x_bf, w1e, bias1, h, 3072,
                                                     768, 12);
  gemm256<false, false><<<480, 512, 131072, stream>>>(h, w2e, bias2, out, 768,
                                                      3072, 3);
}

// Round 4
// 713.758 us; speedup vs baseline: 1.2928x; 1.0400x over previous
//
#include <hip/hip_runtime.h>

typedef __attribute__((ext_vector_type(8))) short short8;
typedef __attribute__((ext_vector_type(4))) float f32x4;

__device__ __forceinline__ unsigned short f2bf(float f) {
  union { float f; unsigned u; } v; v.f = f;
  unsigned r = v.u + 0x7fffu + ((v.u >> 16) & 1u);
  return (unsigned short)(r >> 16);
}

__device__ __forceinline__ void async16(const void* g, void* l) {
  __builtin_amdgcn_global_load_lds(
      (const __attribute__((address_space(1))) unsigned*)g,
      (__attribute__((address_space(3))) unsigned*)l, 16, 0, 0);
}

#define SBAR() __builtin_amdgcn_sched_barrier(0)
#define MEMFENCE() asm volatile("" ::: "memory")
#define BARRIER() __builtin_amdgcn_s_barrier()
#define WAIT_VM(N) asm volatile("s_waitcnt vmcnt(" #N ")" ::: "memory")

// Exact-GELU via Abramowitz-Stegun 7.1.26 erf (|eps| <= 1.5e-7), ~2x cheaper
// than libdevice erff.
__device__ __forceinline__ float gelu_exact(float v) {
  float s = v * 0.70710678118f;
  float x = fabsf(s);
  float t = 1.0f / (1.0f + 0.3275911f * x);
  float p = t * (0.254829592f +
            t * (-0.284496736f +
            t * (1.421413741f + t * (-1.453152027f + t * 1.061405429f))));
  float er = 1.0f - p * __expf(-x * x);
  er = copysignf(er, s);
  return 0.5f * v * (1.0f + er);
}

// ---------------- fp32 -> bf16 bulk convert ----------------
__global__ void cvt_bf16_kernel(const float4* __restrict__ in,
                                ushort4* __restrict__ out, int n4) {
  int i = blockIdx.x * blockDim.x + threadIdx.x;
  int stride = gridDim.x * blockDim.x;
  for (; i < n4; i += stride) {
    float4 v = in[i];
    ushort4 o;
    o.x = f2bf(v.x); o.y = f2bf(v.y); o.z = f2bf(v.z); o.w = f2bf(v.w);
    out[i] = o;
  }
}

// ---------------- W_eff[e] = W + 2.0 * b[e] @ a[e], output bf16 ----------------
__global__ void make_weff(const float* __restrict__ w,
                          const float* __restrict__ bmat,
                          const float* __restrict__ amat,
                          unsigned short* __restrict__ out,
                          int J, int K) {
  const int e = blockIdx.y;
  const float* a = amat + (size_t)e * 64 * K;
  const float* b = bmat + (size_t)e * J * 64;
  const int j0 = blockIdx.x * 16;
  __shared__ float bs[16][64];
  const int tid = threadIdx.x;
  for (int i = tid; i < 16 * 64; i += 256)
    bs[i >> 6][i & 63] = b[(size_t)(j0 + (i >> 6)) * 64 + (i & 63)];
  __syncthreads();
  for (int k = tid; k < K; k += 256) {
    float acc[16];
#pragma unroll
    for (int jj = 0; jj < 16; ++jj) acc[jj] = 0.f;
    for (int r = 0; r < 64; ++r) {
      float av = a[(size_t)r * K + k];
#pragma unroll
      for (int jj = 0; jj < 16; ++jj) acc[jj] += bs[jj][r] * av;
    }
#pragma unroll
    for (int jj = 0; jj < 16; ++jj) {
      float v = w[(size_t)(j0 + jj) * K + k] + 2.0f * acc[jj];
      out[((size_t)e * J + j0 + jj) * K + k] = f2bf(v);
    }
  }
}

// ---------------- 256x256 software-pipelined 8-phase grouped GEMM -------------
// A: [M][K] bf16, Bw: [2][N][K] bf16 (expert per 256-row M tile), bias f32.
// 8 waves (2M x 4N), BK=64, double-buffered 128 KiB LDS, swizzle
// LDS[row][slot j] holds global chunk j ^ (row&7) (both-sides XOR, 16B slots).
//
// Pipeline: phase p issues ds_reads for phase p+1's MFMA (ping-pong frag sets
// afmX/afmY, bfvX/bfvY); MFMA_p consumes last phase's frags -> compiler emits
// counted lgkmcnt, overlapping LDS drain with MFMA. ONE barrier per phase.
//
// MFMA quadrants: P1/P5:(X,X->0,0) P2/P6:(X,Y->0,2) P3/P7:(Y,X->4,0)
// P4/P8:(Y,Y->4,2).  afmX=A h0, afmY=A h1, bfvX=B h0, bfvY=B h1.
// Stages: P1:A1h1(t1) P2:B1h1(t1) P3:A0h0(t+2) P4:B0h0 P5:A0h1 P6:B0h1
//         P7:A1h0(t+3) P8:B1h0(t+3).
// Syncs (before closing barrier): P3 vmcnt(6) [drains <=prev-P8 -> P4 reads
// As1h0/Bs1h0 safe], P4 vmcnt(4) [drains P1,P2 -> P5/P6 read Bs1h1/As1h1],
// P7 vmcnt(6) [drains P3,P4 -> P8 reads As0h0/Bs0h0], P8 vmcnt(4) [drains
// P5,P6 -> next P1/P2 read Bs0h1/As0h1]. All restages are >=1 barrier after
// the consuming MFMA's lgkm-wait (WAR safe).

#define STAGE(Xp, Xs, half, ob)                                                \
  do {                                                                         \
    const char* _g = (const char*)((Xp) + (size_t)((half) * 128) * K) +        \
                     gbyte + (ob);                                             \
    unsigned short* _l = (Xs) + (half) * 8192 + loff;                          \
    async16(_g, _l);                                                           \
    async16(_g + (size_t)K * 128, _l + 4096);                                  \
  } while (0)

#define RDA_TO(dst, Xs, hoff)                                                  \
  _Pragma("unroll") for (int m_ = 0; m_ < 4; ++m_)                             \
  _Pragma("unroll") for (int kk_ = 0; kk_ < 2; ++kk_)                          \
      dst[m_][kk_] = *(const short8*)((const char*)(Xs) + (hoff) * 16384 +     \
                                      arowB + m_ * 2048 + cb[kk_]);

#define RDB_TO(dst, Xs, hoff)                                                  \
  _Pragma("unroll") for (int n_ = 0; n_ < 2; ++n_)                             \
  _Pragma("unroll") for (int kk_ = 0; kk_ < 2; ++kk_)                          \
      dst[n_][kk_] = *(const short8*)((const char*)(Xs) + (hoff) * 16384 +     \
                                      browB + n_ * 2048 + cb[kk_]);

#define MFMAQ(af, bf, mbase, nbase)                                            \
  __builtin_amdgcn_s_setprio(1);                                               \
  _Pragma("unroll") for (int m_ = 0; m_ < 4; ++m_)                             \
  _Pragma("unroll") for (int n_ = 0; n_ < 2; ++n_)                             \
  _Pragma("unroll") for (int kk_ = 0; kk_ < 2; ++kk_)                          \
      acc[(mbase) + m_][(nbase) + n_] =                                        \
          __builtin_amdgcn_mfma_f32_16x16x32_bf16(                             \
              af[m_][kk_], bf[n_][kk_],                                        \
              acc[(mbase) + m_][(nbase) + n_], 0, 0, 0);                       \
  __builtin_amdgcn_s_setprio(0);

#define PHASE_END()                                                            \
  do { SBAR(); MEMFENCE(); BARRIER(); SBAR(); MEMFENCE(); } while (0)

template <bool FUSE_GELU, bool OUT_BF16>
__global__ __launch_bounds__(512, 2) void gemm256(
    const unsigned short* __restrict__ A, const unsigned short* __restrict__ Bw,
    const float* __restrict__ bias, void* __restrict__ Cout, int N, int K,
    int NXT) {
  extern __shared__ unsigned short lds[];
  unsigned short* As0 = lds;
  unsigned short* As1 = lds + 16384;
  unsigned short* Bs0 = lds + 32768;
  unsigned short* Bs1 = lds + 49152;

  const int tid = threadIdx.x;
  const int w = tid >> 6, lane = tid & 63;

  // XCD-aware bijective swizzle (gridDim.x % 8 == 0 by construction)
  const int nwg = gridDim.x, bid = blockIdx.x;
  const int qchunk = nwg >> 3;
  const int wg = (bid & 7) * qchunk + (bid >> 3);
  const int by = wg / NXT, bx = wg - by * NXT;
  const int m0 = by << 8, n0 = bx << 8;
  const int e = (m0 % 1280) ? 1 : 0;  // 256-aligned tiles never span experts
  const unsigned short* Ap = A + (size_t)m0 * K;
  const unsigned short* Bp = Bw + ((size_t)e * N + n0) * K;

  const int wr = w >> 2, wc = w & 3;
  const int fr = lane & 15;
  const int swz = (fr & 7) << 4;
  const int cb[2] = {(((lane >> 4) << 4) + 0) ^ swz,
                     (((lane >> 4) << 4) + 64) ^ swz};
  const int arowB = (wr * 64 + fr) * 128;  // byte base of A frag rows (in half)
  const int browB = (wc * 32 + fr) * 128;  // byte base of B frag rows (in half)

  // staging: thread covers row (w*8 + (lane>>3)) + {0,64}, 16B chunk c16
  const int rql = lane >> 3;
  const int c16 = (lane & 7) ^ rql;  // inverse-swizzled source chunk
  const size_t gbyte = ((size_t)(w * 8 + rql) * K + c16 * 8) * 2;  // bytes
  const int loff = w * 512;  // wave-uniform LDS base (HW adds lane*16B)

  f32x4 acc[8][4] = {};
  short8 afmX[4][2], afmY[4][2];
  short8 bfvX[2][2], bfvY[2][2];

  const int T = K >> 6;       // 64-wide K tiles (12 or 48, even, >=4)
  const int niter = T >> 1;
  const int KB2 = K << 1;     // row length in bytes (wrap modulus)

  // ---- prologue: buf0 tile0 full + buf1 tile1 h0(A,B) in flight ----
  STAGE(Ap, As0, 0, 0); STAGE(Bp, Bs0, 0, 0);
  STAGE(Ap, As0, 1, 0); STAGE(Bp, Bs0, 1, 0);
  STAGE(Ap, As1, 0, 128); STAGE(Bp, Bs1, 0, 128);
  SBAR(); WAIT_VM(4); SBAR();
  MEMFENCE(); BARRIER(); SBAR(); MEMFENCE();
  RDA_TO(afmX, As0, 0); RDB_TO(bfvX, Bs0, 0);

  int ob1 = 128, ob2 = 256, ob3 = 384;
  if (ob2 >= KB2) ob2 -= KB2;
  if (ob3 >= KB2) ob3 -= KB2;

  for (int i = 0; i < niter; ++i) {
    // P1: MFMA(0,0) buf0; read bfvY<-Bs0h1; stage A1h1@t1
    RDB_TO(bfvY, Bs0, 1);
    STAGE(Ap, As1, 1, ob1);
    SBAR();
    MFMAQ(afmX, bfvX, 0, 0);
    PHASE_END();
    // P2: MFMA(0,2); read afmY<-As0h1; stage B1h1@t1
    RDA_TO(afmY, As0, 1);
    STAGE(Bp, Bs1, 1, ob1);
    SBAR();
    MFMAQ(afmX, bfvY, 0, 2);
    PHASE_END();
    // P3: MFMA(4,0); stage A0h0@t+2; vmcnt(6)
    STAGE(Ap, As0, 0, ob2);
    SBAR();
    MFMAQ(afmY, bfvX, 4, 0);
    SBAR(); WAIT_VM(6);
    PHASE_END();
    // P4: MFMA(4,2); read afmX<-As1h0, bfvX<-Bs1h0; stage B0h0@t+2; vmcnt(4)
    RDA_TO(afmX, As1, 0); RDB_TO(bfvX, Bs1, 0);
    STAGE(Bp, Bs0, 0, ob2);
    SBAR();
    MFMAQ(afmY, bfvY, 4, 2);
    SBAR(); WAIT_VM(4);
    PHASE_END();
    // P5: MFMA(0,0) buf1; read bfvY<-Bs1h1; stage A0h1@t+2
    RDB_TO(bfvY, Bs1, 1);
    STAGE(Ap, As0, 1, ob2);
    SBAR();
    MFMAQ(afmX, bfvX, 0, 0);
    PHASE_END();
    // P6: MFMA(0,2); read afmY<-As1h1; stage B0h1@t+2
    RDA_TO(afmY, As1, 1);
    STAGE(Bp, Bs0, 1, ob2);
    SBAR();
    MFMAQ(afmX, bfvY, 0, 2);
    PHASE_END();
    // P7: MFMA(4,0); stage A1h0@t+3; vmcnt(6)
    STAGE(Ap, As1, 0, ob3);
    SBAR();
    MFMAQ(afmY, bfvX, 4, 0);
    SBAR(); WAIT_VM(6);
    PHASE_END();
    // P8: MFMA(4,2); read afmX<-As0h0(t+2), bfvX<-Bs0h0(t+2); stage B1h0@t+3;
    //     vmcnt(4)
    RDA_TO(afmX, As0, 0); RDB_TO(bfvX, Bs0, 0);
    STAGE(Bp, Bs1, 0, ob3);
    SBAR();
    MFMAQ(afmY, bfvY, 4, 2);
    SBAR(); WAIT_VM(4);
    PHASE_END();

    ob1 += 256; if (ob1 >= KB2) ob1 -= KB2;
    ob2 += 256; if (ob2 >= KB2) ob2 -= KB2;
    ob3 += 256; if (ob3 >= KB2) ob3 -= KB2;
  }

  // ---- epilogue: C/D layout col=lane&15, row=(lane>>4)*4+j ----
  const int lrow = (lane >> 4) << 2;
#pragma unroll
  for (int mi = 0; mi < 8; ++mi) {
    const int rbase = m0 + ((mi >> 2) << 7) + wr * 64 + ((mi & 3) << 4) + lrow;
#pragma unroll
    for (int n = 0; n < 4; ++n) {
      const int col = n0 + ((n >> 1) << 7) + wc * 32 + ((n & 1) << 4) + fr;
      const float bv = bias[col];
#pragma unroll
      for (int j = 0; j < 4; ++j) {
        const int row = rbase + j;
        float v = acc[mi][n][j] + bv;
        if (FUSE_GELU) v = gelu_exact(v);
        if (OUT_BF16)
          ((unsigned short*)Cout)[(size_t)row * N + col] = f2bf(v);
        else
          ((float*)Cout)[(size_t)row * N + col] = v;
      }
    }
  }
}

extern "C" void kernel_launch(void* const* d_in, const int* in_sizes, int n_in,
                              void* d_out, int out_size, void* d_ws,
                              size_t ws_size, hipStream_t stream) {
  const float* x = (const float*)d_in[0];
  const float* w1 = (const float*)d_in[1];
  const float* bias1 = (const float*)d_in[2];
  const float* a1 = (const float*)d_in[3];
  const float* b1 = (const float*)d_in[4];
  const float* w2 = (const float*)d_in[5];
  const float* bias2 = (const float*)d_in[6];
  const float* a2 = (const float*)d_in[7];
  const float* b2 = (const float*)d_in[8];
  float* out = (float*)d_out;

  char* ws = (char*)d_ws;
  unsigned short* x_bf = (unsigned short*)(ws + 0);        // 40960*768 bf16
  unsigned short* w1e = (unsigned short*)(ws + 62914560);  // 2*3072*768 bf16
  unsigned short* w2e = (unsigned short*)(ws + 72351744);  // 2*768*3072 bf16
  unsigned short* h = (unsigned short*)(ws + 81788928);    // 40960*3072 bf16

  hipFuncSetAttribute(reinterpret_cast<const void*>(&gemm256<true, true>),
                      hipFuncAttributeMaxDynamicSharedMemorySize, 131072);
  hipFuncSetAttribute(reinterpret_cast<const void*>(&gemm256<false, false>),
                      hipFuncAttributeMaxDynamicSharedMemorySize, 131072);

  cvt_bf16_kernel<<<4096, 256, 0, stream>>>((const float4*)x, (ushort4*)x_bf,
                                            40960 * 768 / 4);
  make_weff<<<dim3(3072 / 16, 2), 256, 0, stream>>>(w1, b1, a1, w1e, 3072, 768);
  make_weff<<<dim3(768 / 16, 2), 256, 0, stream>>>(w2, b2, a2, w2e, 768, 3072);

  // M=40960 -> 160 M-tiles; GEMM1: 160x12=1920 wgs; GEMM2: 160x3=480 wgs
  gemm256<true, true><<<1920, 512, 131072, stream>>>(x_bf, w1e, bias1, h, 3072,
                                                     768, 12);
  gemm256<false, false><<<480, 512, 131072, stream>>>(h, w2e, bias2, out, 768,
                                                      3072, 3);
}

// Round 5
// 710.223 us; speedup vs baseline: 1.2992x; 1.0050x over previous
//
#include <hip/hip_runtime.h>

typedef __attribute__((ext_vector_type(8))) short short8;
typedef __attribute__((ext_vector_type(4))) float f32x4;

__device__ __forceinline__ unsigned short f2bf(float f) {
  union { float f; unsigned u; } v; v.f = f;
  unsigned r = v.u + 0x7fffu + ((v.u >> 16) & 1u);
  return (unsigned short)(r >> 16);
}

__device__ __forceinline__ void async16(const void* g, void* l) {
  __builtin_amdgcn_global_load_lds(
      (const __attribute__((address_space(1))) unsigned*)g,
      (__attribute__((address_space(3))) unsigned*)l, 16, 0, 0);
}

#define SBAR() __builtin_amdgcn_sched_barrier(0)
#define MEMFENCE() asm volatile("" ::: "memory")
#define BARRIER() __builtin_amdgcn_s_barrier()
#define WAIT_VM(N) asm volatile("s_waitcnt vmcnt(" #N ")" ::: "memory")

// Exact-GELU via Abramowitz-Stegun 7.1.26 erf (|eps| <= 1.5e-7).
__device__ __forceinline__ float gelu_exact(float v) {
  float s = v * 0.70710678118f;
  float x = fabsf(s);
  float t = 1.0f / (1.0f + 0.3275911f * x);
  float p = t * (0.254829592f +
            t * (-0.284496736f +
            t * (1.421413741f + t * (-1.453152027f + t * 1.061405429f))));
  float er = 1.0f - p * __expf(-x * x);
  er = copysignf(er, s);
  return 0.5f * v * (1.0f + er);
}

// ---------------- fp32 -> bf16 bulk convert ----------------
__global__ void cvt_bf16_kernel(const float4* __restrict__ in,
                                ushort4* __restrict__ out, int n4) {
  int i = blockIdx.x * blockDim.x + threadIdx.x;
  int stride = gridDim.x * blockDim.x;
  for (; i < n4; i += stride) {
    float4 v = in[i];
    ushort4 o;
    o.x = f2bf(v.x); o.y = f2bf(v.y); o.z = f2bf(v.z); o.w = f2bf(v.w);
    out[i] = o;
  }
}

// ---------------- W_eff[e] = W + 2.0 * b[e] @ a[e], output bf16 ----------------
__global__ void make_weff(const float* __restrict__ w,
                          const float* __restrict__ bmat,
                          const float* __restrict__ amat,
                          unsigned short* __restrict__ out,
                          int J, int K) {
  const int e = blockIdx.y;
  const float* a = amat + (size_t)e * 64 * K;
  const float* b = bmat + (size_t)e * J * 64;
  const int j0 = blockIdx.x * 16;
  __shared__ float bs[16][64];
  const int tid = threadIdx.x;
  for (int i = tid; i < 16 * 64; i += 256)
    bs[i >> 6][i & 63] = b[(size_t)(j0 + (i >> 6)) * 64 + (i & 63)];
  __syncthreads();
  for (int k = tid; k < K; k += 256) {
    float acc[16];
#pragma unroll
    for (int jj = 0; jj < 16; ++jj) acc[jj] = 0.f;
    for (int r = 0; r < 64; ++r) {
      float av = a[(size_t)r * K + k];
#pragma unroll
      for (int jj = 0; jj < 16; ++jj) acc[jj] += bs[jj][r] * av;
    }
#pragma unroll
    for (int jj = 0; jj < 16; ++jj) {
      float v = w[(size_t)(j0 + jj) * K + k] + 2.0f * acc[jj];
      out[((size_t)e * J + j0 + jj) * K + k] = f2bf(v);
    }
  }
}

// ---------------- 256x256 software-pipelined grouped GEMM ---------------------
// A: [M][K] bf16, Bw: [2][N][K] bf16 (expert per 256-row M tile), bias f32.
// 8 waves (2M x 4N), BK=64, double-buffered 128 KiB LDS, swizzle
// LDS[row][slot j] holds global chunk j ^ (row&7) (both-sides XOR, 16B slots).
//
// Pipeline: phase p issues ds_reads for phase p+1's MFMA (ping-pong frag sets
// afmX/afmY, bfvX/bfvY); MFMA_p consumes last phase's frags (counted lgkm).
// Runtime barriers ONLY at P2/P4/P6/P8 ends (super-phases of 32 MFMA); odd
// boundaries are sched_barrier(0) pins (no runtime cost, preserves program
// order so the in-place frag WAR pairs need no renaming).
//
// Stage schedule: P1:A1h1(t1) P2:B1h1(t1) P3:A0h0(t+2) P4:B0h0 P5:A0h1
// P6:B0h1 P7:A1h0(t+3) P8:B1h0(t+3).
// Reads: P1:bfvY<-Bs0h1 P2:afmY<-As0h1 P4:afmX<-As1h0,bfvX<-Bs1h0
// P5:bfvY<-Bs1h1 P6:afmY<-As1h1 P8:afmX<-As0h0,bfvX<-Bs0h0.
// vmcnt(4) at each even-phase end; FIFO leaves exactly the last 2 half-stages:
//  P2-end drains prev{A1h0,B1h0} (RAW for P4 reads), P4-end drains {A1h1,B1h1}
//  (P5/P6 reads), P6-end drains {A0h0,B0h0} (P8 reads), P8-end drains
//  {A0h1,B0h1} (next P1/P2 reads).
// WAR: every stage's overwritten region had its last reader's MFMA issued
// before a surviving barrier that precedes the stage (min 3-phase gaps).

#define STAGE(Xp, Xs, half, ob)                                                \
  do {                                                                         \
    const char* _g = (const char*)((Xp) + (size_t)((half) * 128) * K) +        \
                     gbyte + (ob);                                             \
    unsigned short* _l = (Xs) + (half) * 8192 + loff;                          \
    async16(_g, _l);                                                           \
    async16(_g + (size_t)K * 128, _l + 4096);                                  \
  } while (0)

#define RDA_TO(dst, Xs, hoff)                                                  \
  _Pragma("unroll") for (int m_ = 0; m_ < 4; ++m_)                             \
  _Pragma("unroll") for (int kk_ = 0; kk_ < 2; ++kk_)                          \
      dst[m_][kk_] = *(const short8*)((const char*)(Xs) + (hoff) * 16384 +     \
                                      arowB + m_ * 2048 + cb[kk_]);

#define RDB_TO(dst, Xs, hoff)                                                  \
  _Pragma("unroll") for (int n_ = 0; n_ < 2; ++n_)                             \
  _Pragma("unroll") for (int kk_ = 0; kk_ < 2; ++kk_)                          \
      dst[n_][kk_] = *(const short8*)((const char*)(Xs) + (hoff) * 16384 +     \
                                      browB + n_ * 2048 + cb[kk_]);

#define MFMAQ(af, bf, mbase, nbase)                                            \
  __builtin_amdgcn_s_setprio(1);                                               \
  _Pragma("unroll") for (int m_ = 0; m_ < 4; ++m_)                             \
  _Pragma("unroll") for (int n_ = 0; n_ < 2; ++n_)                             \
  _Pragma("unroll") for (int kk_ = 0; kk_ < 2; ++kk_)                          \
      acc[(mbase) + m_][(nbase) + n_] =                                        \
          __builtin_amdgcn_mfma_f32_16x16x32_bf16(                             \
              af[m_][kk_], bf[n_][kk_],                                        \
              acc[(mbase) + m_][(nbase) + n_], 0, 0, 0);                       \
  __builtin_amdgcn_s_setprio(0);

#define PHASE_END()                                                            \
  do { SBAR(); MEMFENCE(); BARRIER(); SBAR(); MEMFENCE(); } while (0)

template <bool FUSE_GELU, bool OUT_BF16>
__global__ __launch_bounds__(512, 2) void gemm256(
    const unsigned short* __restrict__ A, const unsigned short* __restrict__ Bw,
    const float* __restrict__ bias, void* __restrict__ Cout, int N, int K,
    int NXT) {
  extern __shared__ unsigned short lds[];
  unsigned short* As0 = lds;
  unsigned short* As1 = lds + 16384;
  unsigned short* Bs0 = lds + 32768;
  unsigned short* Bs1 = lds + 49152;

  const int tid = threadIdx.x;
  const int w = tid >> 6, lane = tid & 63;

  // XCD-aware bijective swizzle (gridDim.x % 8 == 0 by construction)
  const int nwg = gridDim.x, bid = blockIdx.x;
  const int qchunk = nwg >> 3;
  const int wg = (bid & 7) * qchunk + (bid >> 3);
  const int by = wg / NXT, bx = wg - by * NXT;
  const int m0 = by << 8, n0 = bx << 8;
  const int e = (m0 % 1280) ? 1 : 0;  // 256-aligned tiles never span experts
  const unsigned short* Ap = A + (size_t)m0 * K;
  const unsigned short* Bp = Bw + ((size_t)e * N + n0) * K;

  const int wr = w >> 2, wc = w & 3;
  const int fr = lane & 15;
  const int swz = (fr & 7) << 4;
  const int cb[2] = {(((lane >> 4) << 4) + 0) ^ swz,
                     (((lane >> 4) << 4) + 64) ^ swz};
  const int arowB = (wr * 64 + fr) * 128;  // byte base of A frag rows (in half)
  const int browB = (wc * 32 + fr) * 128;  // byte base of B frag rows (in half)

  // staging: thread covers row (w*8 + (lane>>3)) + {0,64}, 16B chunk c16
  const int rql = lane >> 3;
  const int c16 = (lane & 7) ^ rql;  // inverse-swizzled source chunk
  const size_t gbyte = ((size_t)(w * 8 + rql) * K + c16 * 8) * 2;  // bytes
  const int loff = w * 512;  // wave-uniform LDS base (HW adds lane*16B)

  f32x4 acc[8][4] = {};
  short8 afmX[4][2], afmY[4][2];
  short8 bfvX[2][2], bfvY[2][2];

  const int T = K >> 6;       // 64-wide K tiles (12 or 48, even, >=4)
  const int niter = T >> 1;
  const int KB2 = K << 1;     // row length in bytes (wrap modulus)

  // ---- prologue: tile0 (8 loads) + {A1h0,B1h0}@t=1 in flight ----
  STAGE(Ap, As0, 0, 0); STAGE(Ap, As0, 1, 0);
  STAGE(Bp, Bs0, 0, 0); STAGE(Bp, Bs0, 1, 0);
  STAGE(Ap, As1, 0, 128); STAGE(Bp, Bs1, 0, 128);
  SBAR(); WAIT_VM(4); SBAR();
  MEMFENCE(); BARRIER(); SBAR(); MEMFENCE();
  RDA_TO(afmX, As0, 0); RDB_TO(bfvX, Bs0, 0);

  int ob1 = 128, ob2 = 256, ob3 = 384;
  if (ob2 >= KB2) ob2 -= KB2;
  if (ob3 >= KB2) ob3 -= KB2;

  for (int i = 0; i < niter; ++i) {
    // P1: MFMA(0,0) buf0; read bfvY<-Bs0h1; stage A1h1@t1
    RDB_TO(bfvY, Bs0, 1);
    STAGE(Ap, As1, 1, ob1);
    SBAR();
    MFMAQ(afmX, bfvX, 0, 0);
    SBAR();
    // P2: MFMA(0,2); read afmY<-As0h1; stage B1h1@t1; vm(4)+barrier
    RDA_TO(afmY, As0, 1);
    STAGE(Bp, Bs1, 1, ob1);
    SBAR();
    MFMAQ(afmX, bfvY, 0, 2);
    SBAR(); WAIT_VM(4);
    PHASE_END();
    // P3: MFMA(4,0); stage A0h0@t+2
    STAGE(Ap, As0, 0, ob2);
    SBAR();
    MFMAQ(afmY, bfvX, 4, 0);
    SBAR();
    // P4: MFMA(4,2); read afmX<-As1h0, bfvX<-Bs1h0; stage B0h0@t+2; vm(4)+bar
    RDA_TO(afmX, As1, 0); RDB_TO(bfvX, Bs1, 0);
    STAGE(Bp, Bs0, 0, ob2);
    SBAR();
    MFMAQ(afmY, bfvY, 4, 2);
    SBAR(); WAIT_VM(4);
    PHASE_END();
    // P5: MFMA(0,0) buf1; read bfvY<-Bs1h1; stage A0h1@t+2
    RDB_TO(bfvY, Bs1, 1);
    STAGE(Ap, As0, 1, ob2);
    SBAR();
    MFMAQ(afmX, bfvX, 0, 0);
    SBAR();
    // P6: MFMA(0,2); read afmY<-As1h1; stage B0h1@t+2; vm(4)+barrier
    RDA_TO(afmY, As1, 1);
    STAGE(Bp, Bs0, 1, ob2);
    SBAR();
    MFMAQ(afmX, bfvY, 0, 2);
    SBAR(); WAIT_VM(4);
    PHASE_END();
    // P7: MFMA(4,0); stage A1h0@t+3
    STAGE(Ap, As1, 0, ob3);
    SBAR();
    MFMAQ(afmY, bfvX, 4, 0);
    SBAR();
    // P8: MFMA(4,2); read afmX<-As0h0(t+2), bfvX<-Bs0h0(t+2); stage B1h0@t+3;
    //     vm(4)+barrier
    RDA_TO(afmX, As0, 0); RDB_TO(bfvX, Bs0, 0);
    STAGE(Bp, Bs1, 0, ob3);
    SBAR();
    MFMAQ(afmY, bfvY, 4, 2);
    SBAR(); WAIT_VM(4);
    PHASE_END();

    ob1 += 256; if (ob1 >= KB2) ob1 -= KB2;
    ob2 += 256; if (ob2 >= KB2) ob2 -= KB2;
    ob3 += 256; if (ob3 >= KB2) ob3 -= KB2;
  }

  // ---- epilogue: C/D layout col=lane&15, row=(lane>>4)*4+j ----
  const int lrow = (lane >> 4) << 2;
#pragma unroll
  for (int mi = 0; mi < 8; ++mi) {
    const int rbase = m0 + ((mi >> 2) << 7) + wr * 64 + ((mi & 3) << 4) + lrow;
#pragma unroll
    for (int n = 0; n < 4; ++n) {
      const int col = n0 + ((n >> 1) << 7) + wc * 32 + ((n & 1) << 4) + fr;
      const float bv = bias[col];
#pragma unroll
      for (int j = 0; j < 4; ++j) {
        const int row = rbase + j;
        float v = acc[mi][n][j] + bv;
        if (FUSE_GELU) v = gelu_exact(v);
        if (OUT_BF16)
          ((unsigned short*)Cout)[(size_t)row * N + col] = f2bf(v);
        else
          ((float*)Cout)[(size_t)row * N + col] = v;
      }
    }
  }
}

extern "C" void kernel_launch(void* const* d_in, const int* in_sizes, int n_in,
                              void* d_out, int out_size, void* d_ws,
                              size_t ws_size, hipStream_t stream) {
  const float* x = (const float*)d_in[0];
  const float* w1 = (const float*)d_in[1];
  const float* bias1 = (const float*)d_in[2];
  const float* a1 = (const float*)d_in[3];
  const float* b1 = (const float*)d_in[4];
  const float* w2 = (const float*)d_in[5];
  const float* bias2 = (const float*)d_in[6];
  const float* a2 = (const float*)d_in[7];
  const float* b2 = (const float*)d_in[8];
  float* out = (float*)d_out;

  char* ws = (char*)d_ws;
  unsigned short* x_bf = (unsigned short*)(ws + 0);        // 40960*768 bf16
  unsigned short* w1e = (unsigned short*)(ws + 62914560);  // 2*3072*768 bf16
  unsigned short* w2e = (unsigned short*)(ws + 72351744);  // 2*768*3072 bf16
  unsigned short* h = (unsigned short*)(ws + 81788928);    // 40960*3072 bf16

  hipFuncSetAttribute(reinterpret_cast<const void*>(&gemm256<true, true>),
                      hipFuncAttributeMaxDynamicSharedMemorySize, 131072);
  hipFuncSetAttribute(reinterpret_cast<const void*>(&gemm256<false, false>),
                      hipFuncAttributeMaxDynamicSharedMemorySize, 131072);

  cvt_bf16_kernel<<<4096, 256, 0, stream>>>((const float4*)x, (ushort4*)x_bf,
                                            40960 * 768 / 4);
  make_weff<<<dim3(3072 / 16, 2), 256, 0, stream>>>(w1, b1, a1, w1e, 3072, 768);
  make_weff<<<dim3(768 / 16, 2), 256, 0, stream>>>(w2, b2, a2, w2e, 768, 3072);

  // M=40960 -> 160 M-tiles; GEMM1: 160x12=1920 wgs; GEMM2: 160x3=480 wgs
  gemm256<true, true><<<1920, 512, 131072, stream>>>(x_bf, w1e, bias1, h, 3072,
                                                     768, 12);
  gemm256<false, false><<<480, 512, 131072, stream>>>(h, w2e, bias2, out, 768,
                                                      3072, 3);
}